// Round 2
// baseline (998.845 us; speedup 1.0000x reference)
//
#include <hip/hip_runtime.h>

typedef unsigned short u16;
typedef __attribute__((ext_vector_type(8))) short s16x8;   // 8 bf16 = 4 VGPR (guide §3)
typedef __attribute__((ext_vector_type(4))) float f32x4;

#define D 2048
#define LORA_SCALE 0.25f   // ALPHA/RANK = 1/4

__device__ __forceinline__ u16 f2bf(float f) {            // fp32 -> bf16 RNE
  unsigned u = __float_as_uint(f);
  unsigned r = u + 0x7fffu + ((u >> 16) & 1u);
  return (u16)(r >> 16);
}
__device__ __forceinline__ float bf2f(u16 h) {
  return __uint_as_float(((unsigned)h) << 16);
}

__device__ __forceinline__ void gload_lds16(const u16* g, u16* l) {
  __builtin_amdgcn_global_load_lds((const __attribute__((address_space(1))) void*)g,
                                   (__attribute__((address_space(3))) void*)l,
                                   16, 0, 0);
}

// ---- split fp32 array into bf16 hi/lo pair (hi = bf16(v), lo = bf16(v - hi)) ----
__global__ void split_fp32(const float* __restrict__ in, u16* __restrict__ hi,
                           u16* __restrict__ lo, int n4) {
  int i = blockIdx.x * 256 + threadIdx.x;
  if (i >= n4) return;
  float4 v = ((const float4*)in)[i];
  ushort4 h, l;
  h.x = f2bf(v.x); l.x = f2bf(v.x - bf2f(h.x));
  h.y = f2bf(v.y); l.y = f2bf(v.y - bf2f(h.y));
  h.z = f2bf(v.z); l.z = f2bf(v.z - bf2f(h.z));
  h.w = f2bf(v.w); l.w = f2bf(v.w - bf2f(h.w));
  ((ushort4*)hi)[i] = h;
  ((ushort4*)lo)[i] = l;
}

// ---- W2eff = W2 + scale * (A @ B_lora), split to bf16 hi/lo ----
// delta[o] = sum_f h[f] * sum_r A[o,r]*B[r,f] * scale  ==> fold into W2 row o.
__global__ void w2eff_split(const float* __restrict__ W2, const float* __restrict__ A,
                            const float* __restrict__ Bl, u16* __restrict__ hi,
                            u16* __restrict__ lo) {
  int idx = blockIdx.x * 256 + threadIdx.x;   // over 2048*512 float4s
  int o = idx >> 9;
  int fq = idx & 511;                          // float4 index within row
  float4 w = ((const float4*)(W2 + o * D))[fq];
  float a0 = A[o * 4 + 0], a1 = A[o * 4 + 1], a2 = A[o * 4 + 2], a3 = A[o * 4 + 3];
  float4 r0 = ((const float4*)(Bl + 0 * D))[fq];
  float4 r1 = ((const float4*)(Bl + 1 * D))[fq];
  float4 r2 = ((const float4*)(Bl + 2 * D))[fq];
  float4 r3 = ((const float4*)(Bl + 3 * D))[fq];
  w.x += LORA_SCALE * (a0 * r0.x + a1 * r1.x + a2 * r2.x + a3 * r3.x);
  w.y += LORA_SCALE * (a0 * r0.y + a1 * r1.y + a2 * r2.y + a3 * r3.y);
  w.z += LORA_SCALE * (a0 * r0.z + a1 * r1.z + a2 * r2.z + a3 * r3.z);
  w.w += LORA_SCALE * (a0 * r0.w + a1 * r1.w + a2 * r2.w + a3 * r3.w);
  ushort4 h, l;
  h.x = f2bf(w.x); l.x = f2bf(w.x - bf2f(h.x));
  h.y = f2bf(w.y); l.y = f2bf(w.y - bf2f(h.y));
  h.z = f2bf(w.z); l.z = f2bf(w.z - bf2f(h.z));
  h.w = f2bf(w.w); l.w = f2bf(w.w - bf2f(h.w));
  ((ushort4*)hi)[idx] = h;
  ((ushort4*)lo)[idx] = l;
}

// ---- split-bf16 GEMM, B^T layout: out[m,n] = sum_k A[m,k]*B[n,k] ----
// 3-term split: Ah*Bh + Ah*Bl + Al*Bh (lo*lo dropped, ~2^-18 rel).
// EPI 0: gelu(acc + bias) -> split bf16 (Oh,Ol).  EPI 1: acc + bias -> fp32 Of.
template <int EPI>
__global__ __launch_bounds__(256, 2) void gemm_bt(
    const u16* __restrict__ Ah, const u16* __restrict__ Al,
    const u16* __restrict__ Bh, const u16* __restrict__ Bl,
    const float* __restrict__ bias,
    u16* __restrict__ Oh, u16* __restrict__ Ol, float* __restrict__ Of) {
  __shared__ u16 lds[2][4][128 * 32];   // [dbuf][Ah,Al,Bh,Bl][128 rows x 32 k] = 64 KiB

  const int tid = threadIdx.x;
  const int brow = blockIdx.y * 128;
  const int bcol = blockIdx.x * 128;
  const int lane = tid & 63;
  const int wid = tid >> 6;
  const int wr = (wid >> 1) * 64;        // wave 2x2 -> each owns 64x64 of the 128x128 tile
  const int wc = (wid & 1) * 64;
  const int frow = lane & 15;            // A/B frag: row = lane&15, k = (lane>>4)*8
  const int fk = (lane >> 4) * 8;

  const int s_row = tid >> 2;            // staging: 4 threads x 16B cover one 64B row
  const int s_seg = (tid & 3) * 8;

  auto stage = [&](const u16* __restrict__ G, int rbase, int kt, u16* L) {
    const u16* g = G + (size_t)(rbase + s_row) * D + kt * 32 + s_seg;
    gload_lds16(g, L + tid * 8);                 // rows 0..63   (lane x 16B, linear)
    gload_lds16(g + 64 * D, L + 2048 + tid * 8); // rows 64..127
  };

  f32x4 acc[4][4];
#pragma unroll
  for (int i = 0; i < 4; ++i)
#pragma unroll
    for (int j = 0; j < 4; ++j) acc[i][j] = (f32x4){0.f, 0.f, 0.f, 0.f};

  stage(Ah, brow, 0, &lds[0][0][0]);
  stage(Al, brow, 0, &lds[0][1][0]);
  stage(Bh, bcol, 0, &lds[0][2][0]);
  stage(Bl, bcol, 0, &lds[0][3][0]);
  __syncthreads();

  for (int kt = 0; kt < D / 32; ++kt) {
    const int b = kt & 1;
    if (kt < D / 32 - 1) {                       // prefetch next K-tile into other buffer
      stage(Ah, brow, kt + 1, &lds[b ^ 1][0][0]);
      stage(Al, brow, kt + 1, &lds[b ^ 1][1][0]);
      stage(Bh, bcol, kt + 1, &lds[b ^ 1][2][0]);
      stage(Bl, bcol, kt + 1, &lds[b ^ 1][3][0]);
    }
    s16x8 ah[4], al[4], bh[4], bl[4];
#pragma unroll
    for (int i = 0; i < 4; ++i) {
      const int off = (wr + i * 16 + frow) * 32 + fk;
      ah[i] = *(const s16x8*)&lds[b][0][off];
      al[i] = *(const s16x8*)&lds[b][1][off];
    }
#pragma unroll
    for (int j = 0; j < 4; ++j) {
      const int off = (wc + j * 16 + frow) * 32 + fk;
      bh[j] = *(const s16x8*)&lds[b][2][off];
      bl[j] = *(const s16x8*)&lds[b][3][off];
    }
#pragma unroll
    for (int i = 0; i < 4; ++i)
#pragma unroll
      for (int j = 0; j < 4; ++j) {
        acc[i][j] = __builtin_amdgcn_mfma_f32_16x16x32_bf16(ah[i], bh[j], acc[i][j], 0, 0, 0);
        acc[i][j] = __builtin_amdgcn_mfma_f32_16x16x32_bf16(ah[i], bl[j], acc[i][j], 0, 0, 0);
        acc[i][j] = __builtin_amdgcn_mfma_f32_16x16x32_bf16(al[i], bh[j], acc[i][j], 0, 0, 0);
      }
    __syncthreads();   // also drains the global_load_lds queue (compiler vmcnt(0))
  }

  // epilogue: C/D layout col = lane&15, row = (lane>>4)*4 + reg  [m89-verified]
  const int r0 = brow + wr + (lane >> 4) * 4;
  const int c0 = bcol + wc + (lane & 15);
#pragma unroll
  for (int j = 0; j < 4; ++j) {
    const int col = c0 + j * 16;
    const float bv = bias[col];
#pragma unroll
    for (int i = 0; i < 4; ++i) {
#pragma unroll
      for (int r = 0; r < 4; ++r) {
        const size_t row = r0 + i * 16 + r;
        float v = acc[i][j][r] + bv;
        if (EPI == 0) {
          // jax.nn.gelu default (approximate=True, tanh form)
          float t = 0.7978845608028654f * v * (1.0f + 0.044715f * v * v);
          float g = 0.5f * v * (1.0f + tanhf(t));
          u16 hh = f2bf(g);
          u16 hl = f2bf(g - bf2f(hh));
          Oh[row * D + col] = hh;
          Ol[row * D + col] = hl;
        } else {
          Of[row * D + col] = v;
        }
      }
    }
  }
}

extern "C" void kernel_launch(void* const* d_in, const int* in_sizes, int n_in,
                              void* d_out, int out_size, void* d_ws, size_t ws_size,
                              hipStream_t stream) {
  const float* x  = (const float*)d_in[0];
  const float* W1 = (const float*)d_in[1];
  const float* b1 = (const float*)d_in[2];
  const float* W2 = (const float*)d_in[3];
  const float* b2 = (const float*)d_in[4];
  const float* A  = (const float*)d_in[5];
  const float* Bl = (const float*)d_in[6];
  float* out = (float*)d_out;

  char* ws = (char*)d_ws;
  const size_t WBUF = (size_t)D * D * sizeof(u16);   // 8 MiB per weight half
  u16* W1h = (u16*)(ws);
  u16* W1l = (u16*)(ws + WBUF);
  u16* W2h = (u16*)(ws + 2 * WBUF);
  u16* W2l = (u16*)(ws + 3 * WBUF);
  char* cb = ws + 4 * WBUF;

  const int M = 16384;
  int CHUNK = M;   // shrink until 4 chunk buffers (Xh,Xl,Hh,Hl) fit in ws
  while (CHUNK > 128 && 4 * WBUF + (size_t)CHUNK * D * 2 * 4 > ws_size) CHUNK >>= 1;

  u16* Xh = (u16*)cb;
  u16* Xl = Xh + (size_t)CHUNK * D;
  u16* Hh = Xl + (size_t)CHUNK * D;
  u16* Hl = Hh + (size_t)CHUNK * D;

  // prep: weight splits (LoRA folded into W2)
  split_fp32<<<dim3((D * D / 4) / 256), 256, 0, stream>>>(W1, W1h, W1l, D * D / 4);
  w2eff_split<<<dim3((D * D / 4) / 256), 256, 0, stream>>>(W2, A, Bl, W2h, W2l);

  for (int c = 0; c < M / CHUNK; ++c) {
    const float* xc = x + (size_t)c * CHUNK * D;
    split_fp32<<<dim3((CHUNK * D / 4) / 256), 256, 0, stream>>>(xc, Xh, Xl, CHUNK * D / 4);
    dim3 grid(D / 128, CHUNK / 128);
    gemm_bt<0><<<grid, 256, 0, stream>>>(Xh, Xl, W1h, W1l, b1, Hh, Hl, nullptr);
    gemm_bt<1><<<grid, 256, 0, stream>>>(Hh, Hl, W2h, W2l, b2, nullptr, nullptr,
                                         out + (size_t)c * CHUNK * D);
  }
}

// Round 7
// 982.265 us; speedup vs baseline: 1.0169x; 1.0169x over previous
//
#include <hip/hip_runtime.h>

typedef unsigned short u16;
typedef __attribute__((ext_vector_type(8))) short s16x8;   // 8 bf16 = 4 VGPR
typedef __attribute__((ext_vector_type(4))) float f32x4;

#define D 2048
#define LORA_SCALE 0.25f   // ALPHA/RANK = 1/4

__device__ __forceinline__ u16 f2bf(float f) {            // fp32 -> bf16 RNE
  unsigned u = __float_as_uint(f);
  unsigned r = u + 0x7fffu + ((u >> 16) & 1u);
  return (u16)(r >> 16);
}
__device__ __forceinline__ float bf2f(u16 h) {
  return __uint_as_float(((unsigned)h) << 16);
}

__device__ __forceinline__ void gload_lds16(const u16* g, u16* l) {
  __builtin_amdgcn_global_load_lds((const __attribute__((address_space(1))) void*)g,
                                   (__attribute__((address_space(3))) void*)l,
                                   16, 0, 0);
}

// ---- split fp32 array into bf16 hi/lo pair ----
__global__ void split_fp32(const float* __restrict__ in, u16* __restrict__ hi,
                           u16* __restrict__ lo, int n4) {
  int i = blockIdx.x * 256 + threadIdx.x;
  if (i >= n4) return;
  float4 v = ((const float4*)in)[i];
  ushort4 h, l;
  h.x = f2bf(v.x); l.x = f2bf(v.x - bf2f(h.x));
  h.y = f2bf(v.y); l.y = f2bf(v.y - bf2f(h.y));
  h.z = f2bf(v.z); l.z = f2bf(v.z - bf2f(h.z));
  h.w = f2bf(v.w); l.w = f2bf(v.w - bf2f(h.w));
  ((ushort4*)hi)[i] = h;
  ((ushort4*)lo)[i] = l;
}

// ---- W2eff = W2 + scale * (A @ B_lora), split to bf16 hi/lo ----
__global__ void w2eff_split(const float* __restrict__ W2, const float* __restrict__ A,
                            const float* __restrict__ Bl, u16* __restrict__ hi,
                            u16* __restrict__ lo) {
  int idx = blockIdx.x * 256 + threadIdx.x;
  int o = idx >> 9;
  int fq = idx & 511;
  float4 w = ((const float4*)(W2 + o * D))[fq];
  float a0 = A[o * 4 + 0], a1 = A[o * 4 + 1], a2 = A[o * 4 + 2], a3 = A[o * 4 + 3];
  float4 r0 = ((const float4*)(Bl + 0 * D))[fq];
  float4 r1 = ((const float4*)(Bl + 1 * D))[fq];
  float4 r2 = ((const float4*)(Bl + 2 * D))[fq];
  float4 r3 = ((const float4*)(Bl + 3 * D))[fq];
  w.x += LORA_SCALE * (a0 * r0.x + a1 * r1.x + a2 * r2.x + a3 * r3.x);
  w.y += LORA_SCALE * (a0 * r0.y + a1 * r1.y + a2 * r2.y + a3 * r3.y);
  w.z += LORA_SCALE * (a0 * r0.z + a1 * r1.z + a2 * r2.z + a3 * r3.z);
  w.w += LORA_SCALE * (a0 * r0.w + a1 * r1.w + a2 * r2.w + a3 * r3.w);
  ushort4 h, l;
  h.x = f2bf(w.x); l.x = f2bf(w.x - bf2f(h.x));
  h.y = f2bf(w.y); l.y = f2bf(w.y - bf2f(h.y));
  h.z = f2bf(w.z); l.z = f2bf(w.z - bf2f(h.z));
  h.w = f2bf(w.w); l.w = f2bf(w.w - bf2f(h.w));
  ((ushort4*)hi)[idx] = h;
  ((ushort4*)lo)[idx] = l;
}

// ---- split-3 GEMM as virtual-K' plain GEMM: A'=[Ah|Ah|Al], B'=[Bh|Bl|Bh], K'=6144 ----
// BM=BN=256, BK=32, 8 waves (2Mx4N), 3-buf LDS ring, counted vmcnt(4), XOR swizzle.
// EPI 0: gelu(acc+bias) -> (Oh,Ol).  EPI 1: acc+bias -> fp32 Of.
template <int EPI>
__global__ __launch_bounds__(512, 2) void gemm8p(
    const u16* __restrict__ Ah, const u16* __restrict__ Al,
    const u16* __restrict__ Bh, const u16* __restrict__ Bl,
    const float* __restrict__ bias,
    u16* __restrict__ Oh, u16* __restrict__ Ol, float* __restrict__ Of) {
  __shared__ u16 lds[3][2][256 * 32];   // 96 KiB: [ring][A,B][256 rows x 32 k]

  const int tid  = threadIdx.x;
  const int lane = tid & 63;
  const int wid  = tid >> 6;
  const int wrow = wid >> 2;            // 0..1  -> 128 M-rows each
  const int wcol = wid & 3;             // 0..3  -> 64  N-cols each

  // XCD-aware bijective swizzle (nwg % 8 == 0 always: nwg = (CHUNK/256)*8)
  const int nwg = gridDim.x;
  const int cpx = nwg >> 3;
  const int swz = ((int)blockIdx.x & 7) * cpx + ((int)blockIdx.x >> 3);
  const int brow = (swz >> 3) * 256;    // N-tiles fastest -> neighbor blocks share A-panel
  const int bcol = (swz & 7) * 256;

  // staging: thread -> row tid>>2 (0..127), 16B slot tid&3 (linear LDS dest);
  // SOURCE slot pre-XORed with key=(row>>1)&3  [(tid>>3)&3 == (srow>>1)&3]  (rule #21)
  const int srow  = tid >> 2;
  const int sslot = (tid & 3) ^ ((tid >> 3) & 3);
  // read side: k-chunk u = lane>>4, same XOR key from row bits -> conflict-free b128
  const int uswz = (((lane >> 4) ^ ((lane & 15) >> 1)) & 3) << 4;

  auto stageA = [&](int t, int rb) {
    const u16* g = ((t < 128) ? Ah : Al) +
                   (size_t)(brow + srow) * D + (t & 63) * 32 + sslot * 8;
    u16* l = &lds[rb][0][0];
    gload_lds16(g, l + tid * 8);                           // rows 0..127
    gload_lds16(g + (size_t)128 * D, l + 4096 + tid * 8);  // rows 128..255
  };
  auto stageB = [&](int t, int rb) {
    const u16* g = ((t < 64) ? Bh : ((t < 128) ? Bl : Bh)) +
                   (size_t)(bcol + srow) * D + (t & 63) * 32 + sslot * 8;
    u16* l = &lds[rb][1][0];
    gload_lds16(g, l + tid * 8);
    gload_lds16(g + (size_t)128 * D, l + 4096 + tid * 8);
  };
  auto rdA = [&](int rb, int r) -> s16x8 {                 // r = local row 0..255
    return *(const s16x8*)((const char*)&lds[rb][0][0] + r * 64 + uswz);
  };
  auto rdB = [&](int rb, int r) -> s16x8 {
    return *(const s16x8*)((const char*)&lds[rb][1][0] + r * 64 + uswz);
  };

  f32x4 acc[8][4];
#pragma unroll
  for (int i = 0; i < 8; ++i)
#pragma unroll
    for (int j = 0; j < 4; ++j) acc[i][j] = (f32x4){0.f, 0.f, 0.f, 0.f};

  // prologue: stage tiles 0,1; confirm tile 0 (4 newest loads may stay in flight)
  stageA(0, 0); stageB(0, 0);
  stageA(1, 1); stageB(1, 1);
  asm volatile("s_waitcnt vmcnt(4)" ::: "memory");
  __builtin_amdgcn_s_barrier();
  __builtin_amdgcn_sched_barrier(0);

  const int T = 192;                    // K' = 6144 / BK=32
  const int l15 = lane & 15;
  int cur = 0;
  s16x8 bf[4];
  for (int t = 0; t < T; ++t) {
    const int nb = (cur >= 1) ? cur - 1 : cur + 2;    // (t+2) % 3
    const int ts = (t + 2 < T) ? (t + 2) : (T - 1);   // branch-free tail (restage ok)

    // ---- phase A (m-half 0): ds-reads || stageA -> barrier -> MFMA ----
    s16x8 af0 = rdA(cur, wrow * 128 + 0 * 16 + l15);
    s16x8 af1 = rdA(cur, wrow * 128 + 1 * 16 + l15);
    s16x8 af2 = rdA(cur, wrow * 128 + 2 * 16 + l15);
    s16x8 af3 = rdA(cur, wrow * 128 + 3 * 16 + l15);
#pragma unroll
    for (int j = 0; j < 4; ++j) bf[j] = rdB(cur, wcol * 64 + j * 16 + l15);
    stageA(ts, nb);
    __builtin_amdgcn_s_barrier();
    __builtin_amdgcn_sched_barrier(0);
    __builtin_amdgcn_s_setprio(1);
#pragma unroll
    for (int j = 0; j < 4; ++j) {
      acc[0][j] = __builtin_amdgcn_mfma_f32_16x16x32_bf16(af0, bf[j], acc[0][j], 0, 0, 0);
      acc[1][j] = __builtin_amdgcn_mfma_f32_16x16x32_bf16(af1, bf[j], acc[1][j], 0, 0, 0);
      acc[2][j] = __builtin_amdgcn_mfma_f32_16x16x32_bf16(af2, bf[j], acc[2][j], 0, 0, 0);
      acc[3][j] = __builtin_amdgcn_mfma_f32_16x16x32_bf16(af3, bf[j], acc[3][j], 0, 0, 0);
    }
    __builtin_amdgcn_s_setprio(0);
    __builtin_amdgcn_s_barrier();
    __builtin_amdgcn_sched_barrier(0);

    // ---- phase B (m-half 1): reuse bf regs; ds-reads || stageB -> barrier -> MFMA ----
    s16x8 ag0 = rdA(cur, wrow * 128 + 64 + 0 * 16 + l15);
    s16x8 ag1 = rdA(cur, wrow * 128 + 64 + 1 * 16 + l15);
    s16x8 ag2 = rdA(cur, wrow * 128 + 64 + 2 * 16 + l15);
    s16x8 ag3 = rdA(cur, wrow * 128 + 64 + 3 * 16 + l15);
    stageB(ts, nb);
    __builtin_amdgcn_s_barrier();
    __builtin_amdgcn_sched_barrier(0);
    __builtin_amdgcn_s_setprio(1);
#pragma unroll
    for (int j = 0; j < 4; ++j) {
      acc[4][j] = __builtin_amdgcn_mfma_f32_16x16x32_bf16(ag0, bf[j], acc[4][j], 0, 0, 0);
      acc[5][j] = __builtin_amdgcn_mfma_f32_16x16x32_bf16(ag1, bf[j], acc[5][j], 0, 0, 0);
      acc[6][j] = __builtin_amdgcn_mfma_f32_16x16x32_bf16(ag2, bf[j], acc[6][j], 0, 0, 0);
      acc[7][j] = __builtin_amdgcn_mfma_f32_16x16x32_bf16(ag3, bf[j], acc[7][j], 0, 0, 0);
    }
    __builtin_amdgcn_s_setprio(0);
    // tile boundary: confirm tile t+1 landed (its 4 loads are oldest in flight)
    asm volatile("s_waitcnt vmcnt(4)" ::: "memory");
    __builtin_amdgcn_s_barrier();
    __builtin_amdgcn_sched_barrier(0);

    cur = (cur + 1 >= 3) ? 0 : cur + 1;
  }

  // drain pending global_load_lds before block can retire (LDS-reuse hazard)
  asm volatile("s_waitcnt vmcnt(0)" ::: "memory");

  // epilogue: C/D frag layout col = lane&15, row = (lane>>4)*4 + reg  [m89]
  const int r0 = brow + wrow * 128 + (lane >> 4) * 4;
  const int c0 = bcol + wcol * 64 + l15;
#pragma unroll
  for (int j = 0; j < 4; ++j) {
    const int col = c0 + j * 16;
    const float bv = bias[col];
#pragma unroll
    for (int i = 0; i < 8; ++i) {
#pragma unroll
      for (int r = 0; r < 4; ++r) {
        const size_t row = r0 + i * 16 + r;
        float v = acc[i][j][r] + bv;
        if (EPI == 0) {
          // jax.nn.gelu (approximate=True, tanh form)
          float tt = 0.7978845608028654f * v * (1.0f + 0.044715f * v * v);
          float g = 0.5f * v * (1.0f + tanhf(tt));
          u16 hh = f2bf(g);
          u16 hl = f2bf(g - bf2f(hh));
          Oh[row * D + col] = hh;
          Ol[row * D + col] = hl;
        } else {
          Of[row * D + col] = v;
        }
      }
    }
  }
}

extern "C" void kernel_launch(void* const* d_in, const int* in_sizes, int n_in,
                              void* d_out, int out_size, void* d_ws, size_t ws_size,
                              hipStream_t stream) {
  const float* x  = (const float*)d_in[0];
  const float* W1 = (const float*)d_in[1];
  const float* b1 = (const float*)d_in[2];
  const float* W2 = (const float*)d_in[3];
  const float* b2 = (const float*)d_in[4];
  const float* A  = (const float*)d_in[5];
  const float* Bl = (const float*)d_in[6];
  float* out = (float*)d_out;

  char* ws = (char*)d_ws;
  const size_t WBUF = (size_t)D * D * sizeof(u16);
  u16* W1h = (u16*)(ws);
  u16* W1l = (u16*)(ws + WBUF);
  u16* W2h = (u16*)(ws + 2 * WBUF);
  u16* W2l = (u16*)(ws + 3 * WBUF);
  char* cb = ws + 4 * WBUF;

  const int M = 16384;
  int CHUNK = M;   // shrink until 4 chunk buffers fit (tile needs CHUNK % 256 == 0)
  while (CHUNK > 256 && 4 * WBUF + (size_t)CHUNK * D * 2 * 4 > ws_size) CHUNK >>= 1;

  u16* Xh = (u16*)cb;
  u16* Xl = Xh + (size_t)CHUNK * D;
  u16* Hh = Xl + (size_t)CHUNK * D;
  u16* Hl = Hh + (size_t)CHUNK * D;

  split_fp32<<<dim3((D * D / 4) / 256), 256, 0, stream>>>(W1, W1h, W1l, D * D / 4);
  w2eff_split<<<dim3((D * D / 4) / 256), 256, 0, stream>>>(W2, A, Bl, W2h, W2l);

  for (int c = 0; c < M / CHUNK; ++c) {
    const float* xc = x + (size_t)c * CHUNK * D;
    split_fp32<<<dim3((CHUNK * D / 4) / 256), 256, 0, stream>>>(xc, Xh, Xl, CHUNK * D / 4);
    dim3 grid((CHUNK / 256) * (D / 256));
    gemm8p<0><<<grid, 512, 0, stream>>>(Xh, Xl, W1h, W1l, b1, Hh, Hl, nullptr);
    gemm8p<1><<<grid, 512, 0, stream>>>(Hh, Hl, W2h, W2l, b2, nullptr, nullptr,
                                        out + (size_t)c * CHUNK * D);
  }
}